// Round 1
// baseline (447.983 us; speedup 1.0000x reference)
//
#include <hip/hip_runtime.h>
#include <hip/hip_bf16.h>
#include <stdint.h>

// Problem constants
#define BATCH   8192
#define IN_DIM  1024
#define N_HID   2048
#define OUT_DIM 256
#define SRC_DIM 3072

// Tiling
#define C     32                   // source columns per chunk
#define RB    8                    // rows per row-block (= rows per wave)
#define BT    256                  // batch per block (4 per lane: 2l, 2l+1, 128+2l, 128+2l+1)
#define S1_CH (IN_DIM / C)         // 32
#define S1_RB (N_HID / RB)         // 256
#define S2_CH (SRC_DIM / C)        // 96
#define S2_RB (OUT_DIM / RB)       // 32
#define NSEG1 (S1_RB * S1_CH)      // 8192
#define NSEG2 (S2_RB * S2_CH)      // 3072
#define SEG_U32 128                // segment stride (512 B)

// Segment format v4 (RB=8, fully gated -> ZERO pad slot reads):
//   u32[0]      plane-0 mask: bit r = row r has >=1 edge
//   u32[1..2]   plane-0 slot bytes, row r at byte r (8 bytes)
//   planes p=1.. at word 3+5(p-1):
//     [0] = maskA (bits 0-7: n >= 2p) | maskB<<8 (bits 8-15: n >= 2p+1)
//     [1..4] = u16 per row: slot bytes for overflow indices 2p-1, 2p
//   hdr: W = 1 + floor(max_n/2), wave-uniform.
// All record/mask loads are wave-uniform -> scalar path; gating is scalar
// branches (SALU), DS reads = real edges exactly (1.6/row vs v3's 2.87).

// A-tile: slot s (= act*32+col, 0..127) * 512 B; lane l reads ds_read_b64 at
// byte s*512 + 8l = bf16 pairs for batches (2l,2l+1) and (128+2l,128+2l+1).
// 128 slots * 512 B = exactly 64 KB -> 2 blocks/CU.

// ---------------------------------------------------------------------------
__global__ void k_prep(const int* __restrict__ mat,
                       uint32_t* __restrict__ seg1, uint32_t* __restrict__ seg2,
                       uint32_t* __restrict__ hdr1, uint32_t* __restrict__ hdr2) {
    int wid  = (blockIdx.x * blockDim.x + threadIdx.x) >> 6;
    int lane = threadIdx.x & 63;
    if (wid >= NSEG1 + NSEG2) return;

    int row0, col0;
    uint32_t *seg, *hdr;
    if (wid < NSEG1) {
        int rb = wid / S1_CH, ch = wid % S1_CH;
        row0 = rb * RB;          col0 = ch * C;
        seg = seg1 + (size_t)wid * SEG_U32;  hdr = hdr1 + wid;
    } else {
        int s  = wid - NSEG1;
        int rb = s / S2_CH, ch = s % S2_CH;
        row0 = N_HID + rb * RB;  col0 = ch * C;
        seg = seg2 + (size_t)s * SEG_U32;    hdr = hdr2 + s;
    }

    int n = 0;
    if (lane < RB) {
        const int* mrow = mat + (size_t)(row0 + lane) * SRC_DIM + col0;
        uint8_t* sb = (uint8_t*)seg;
        for (int c = 0; c < C; c++) {
            int code = mrow[c];
            if (code != 0) {
                uint8_t slot = (uint8_t)((code - 1) * C + c);
                if (n == 0) {
                    sb[4 + lane] = slot;                      // plane-0 byte
                } else {
                    int j  = n - 1;                           // overflow index
                    int pl = j >> 1;                          // plane-1 index
                    sb[(size_t)(3 + 5 * pl + 1) * 4 + 2 * lane + (j & 1)] = slot;
                }
                n++;
            }
        }
    }
    int m = n;
    #pragma unroll
    for (int d = 1; d < 64; d <<= 1) m = max(m, __shfl_xor(m, d));
    uint32_t Wv = 1u + (uint32_t)(m >> 1);

    {
        unsigned long long b = __ballot(n >= 1);
        if (lane == 0) seg[0] = (uint32_t)(b & 0xFFu);
    }
    for (uint32_t p = 1; p < Wv; p++) {
        unsigned long long a = __ballot(n >= (int)(2 * p));
        unsigned long long b = __ballot(n >= (int)(2 * p + 1));
        if (lane == 0)
            seg[3 + 5 * (p - 1)] = (uint32_t)((a & 0xFFu) | ((b & 0xFFu) << 8));
    }
    if (lane == 0) *hdr = Wv;
}

// ---------------------------------------------------------------------------
// k_xt: transpose x[8192][1024] -> x_t[1024][8192] (fp32), 64x64 LDS tiles.
// ---------------------------------------------------------------------------
__global__ __launch_bounds__(256) void k_xt(const float* __restrict__ x,
                                            float* __restrict__ x_t) {
    __shared__ float t[64][65];
    const int b0 = blockIdx.x * 64, c0 = blockIdx.y * 64;
    {
        int r  = threadIdx.x >> 4;
        int cq = (threadIdx.x & 15) * 4;
        #pragma unroll
        for (int k = 0; k < 4; k++) {
            int rr = r + 16 * k;
            float4 v = *(const float4*)&x[(size_t)(b0 + rr) * IN_DIM + c0 + cq];
            t[rr][cq + 0] = v.x; t[rr][cq + 1] = v.y;
            t[rr][cq + 2] = v.z; t[rr][cq + 3] = v.w;
        }
    }
    __syncthreads();
    {
        int bq  = (threadIdx.x & 15) * 4;
        int cc0 = threadIdx.x >> 4;
        #pragma unroll
        for (int k = 0; k < 4; k++) {
            int cc = cc0 + 16 * k;
            float4 v;
            v.x = t[bq + 0][cc]; v.y = t[bq + 1][cc];
            v.z = t[bq + 2][cc]; v.w = t[bq + 3][cc];
            *(float4*)&x_t[(size_t)(c0 + cc) * BATCH + b0 + bq] = v;
        }
    }
}

// pack two floats as bf16 pair: low16 = first, high16 = second
__device__ __forceinline__ uint32_t pack2(float a, float b) {
    __hip_bfloat162 h = __float22bfloat162_rn(make_float2(a, b));
    union { __hip_bfloat162 h2; uint32_t u; } u;
    u.h2 = h;
    return u.u;
}

// write 4 activation slots for column c, 4 batches per lane (v pre-scaled by w)
__device__ __forceinline__ void write_acts4(uint32_t* As, int c, int lane, float4 v) {
    *(uint2*)&As[(size_t)(0 * C + c) * 128 + 2 * lane] =
        make_uint2(pack2(v.x, v.y), pack2(v.z, v.w));
    *(uint2*)&As[(size_t)(1 * C + c) * 128 + 2 * lane] =
        make_uint2(pack2(fmaxf(v.x, 0.0f), fmaxf(v.y, 0.0f)),
                   pack2(fmaxf(v.z, 0.0f), fmaxf(v.w, 0.0f)));
    float tx = 1.0f - 2.0f / (__expf(2.0f * v.x) + 1.0f);
    float ty = 1.0f - 2.0f / (__expf(2.0f * v.y) + 1.0f);
    float tz = 1.0f - 2.0f / (__expf(2.0f * v.z) + 1.0f);
    float tw = 1.0f - 2.0f / (__expf(2.0f * v.w) + 1.0f);
    *(uint2*)&As[(size_t)(2 * C + c) * 128 + 2 * lane] =
        make_uint2(pack2(tx, ty), pack2(tz, tw));
    float sx = 1.0f / (1.0f + __expf(-v.x));
    float sy = 1.0f / (1.0f + __expf(-v.y));
    float sz = 1.0f / (1.0f + __expf(-v.z));
    float sw = 1.0f / (1.0f + __expf(-v.w));
    *(uint2*)&As[(size_t)(3 * C + c) * 128 + 2 * lane] =
        make_uint2(pack2(sx, sy), pack2(sz, sw));
}

// one slot: ds_read_b64 -> 2 bf16-pairs -> 2 packed f32 adds (4 batches)
#define SLOT_ACC(AR, BR, S)                                                    \
    {                                                                          \
        uint2 q_ = *(const uint2*)&As[(size_t)(S) * 128 + 2 * lane];           \
        (AR).x += __uint_as_float(q_.x << 16);                                 \
        (AR).y += __uint_as_float(q_.x & 0xFFFF0000u);                         \
        (BR).x += __uint_as_float(q_.y << 16);                                 \
        (BR).y += __uint_as_float(q_.y & 0xFFFF0000u);                         \
    }

#define EDGE_PLANES(SEGBASE, WVAL)                                             \
    {                                                                          \
        const uint32_t* sp_ = (SEGBASE);                                       \
        uint32_t m0_ = sp_[0];                                                 \
        uint32_t g0_ = sp_[1], g1_ = sp_[2];                                   \
        if (m0_ & 1u)   SLOT_ACC(accA[0], accB[0], g0_ & 255u)                 \
        if (m0_ & 2u)   SLOT_ACC(accA[1], accB[1], (g0_ >> 8) & 255u)          \
        if (m0_ & 4u)   SLOT_ACC(accA[2], accB[2], (g0_ >> 16) & 255u)         \
        if (m0_ & 8u)   SLOT_ACC(accA[3], accB[3], g0_ >> 24)                  \
        if (m0_ & 16u)  SLOT_ACC(accA[4], accB[4], g1_ & 255u)                 \
        if (m0_ & 32u)  SLOT_ACC(accA[5], accB[5], (g1_ >> 8) & 255u)          \
        if (m0_ & 64u)  SLOT_ACC(accA[6], accB[6], (g1_ >> 16) & 255u)         \
        if (m0_ & 128u) SLOT_ACC(accA[7], accB[7], g1_ >> 24)                  \
        for (uint32_t p_ = 1; p_ < (WVAL); p_++) {                             \
            const uint32_t* pp_ = sp_ + 3 + 5 * (p_ - 1);                      \
            uint32_t mk_ = pp_[0];                                             \
            _Pragma("unroll")                                                  \
            for (int r_ = 0; r_ < RB; r_++) {                                  \
                if (mk_ & (1u << r_)) {                                        \
                    uint32_t h_ = pp_[1 + (r_ >> 1)];                          \
                    uint32_t u_ = (r_ & 1) ? (h_ >> 16) : h_;                  \
                    SLOT_ACC(accA[r_], accB[r_], u_ & 255u)                    \
                    if (mk_ & (0x100u << r_))                                  \
                        SLOT_ACC(accA[r_], accB[r_], (u_ >> 8) & 255u)         \
                }                                                              \
            }                                                                  \
        }                                                                      \
    }

// ---------------------------------------------------------------------------
// Stage 1: 1024 thr = 16 waves x 8 rows = 128 rows; 256 batches per block.
// Grid (32 tiles, 16 row splits). LDS = 64 KB A-tile, 2 blocks/CU (32 waves).
// ---------------------------------------------------------------------------
__global__ __launch_bounds__(1024, 8) void k_hid(const float* __restrict__ x_t,
                                                 const float* __restrict__ wp,
                                                 const uint32_t* __restrict__ seg1,
                                                 const uint32_t* __restrict__ hdr1,
                                                 __hip_bfloat16* __restrict__ hidden_t) {
    __shared__ uint32_t As[4 * C * 128];        // exactly 64 KB

    const float w  = wp[0];
    const int tile = blockIdx.x;                // 0..31
    const int lane = threadIdx.x & 63;
    const int wv   = __builtin_amdgcn_readfirstlane(threadIdx.x >> 6); // 0..15
    const int rb   = blockIdx.y * 16 + wv;      // row-block 0..255
    const int b0   = tile * BT;

    float2 accA[RB], accB[RB];
    #pragma unroll
    for (int r = 0; r < RB; r++) {
        accA[r] = make_float2(0.0f, 0.0f);
        accB[r] = make_float2(0.0f, 0.0f);
    }

    // prefetch chunk 0: each wave owns 2 columns, 4 batches/lane
    float4 v[2];
    #pragma unroll
    for (int j = 0; j < 2; j++) {
        int gcol = wv * 2 + j;
        const float2* xp = (const float2*)&x_t[(size_t)gcol * BATCH + b0];
        float2 u0 = xp[lane], u1 = xp[64 + lane];
        v[j] = make_float4(w * u0.x, w * u0.y, w * u1.x, w * u1.y);
    }

    #pragma unroll 1
    for (int ch = 0; ch < S1_CH; ch++) {
        __syncthreads();                        // edge-phase(ch-1) done
        write_acts4(As, wv * 2 + 0, lane, v[0]);
        write_acts4(As, wv * 2 + 1, lane, v[1]);
        __syncthreads();                        // acts visible
        if (ch + 1 < S1_CH) {                   // prefetch next chunk
            #pragma unroll
            for (int j = 0; j < 2; j++) {
                int gcol = (ch + 1) * C + wv * 2 + j;
                const float2* xp = (const float2*)&x_t[(size_t)gcol * BATCH + b0];
                float2 u0 = xp[lane], u1 = xp[64 + lane];
                v[j] = make_float4(w * u0.x, w * u0.y, w * u1.x, w * u1.y);
            }
        }
        int sidx = rb * S1_CH + ch;
        uint32_t W = hdr1[sidx];
        EDGE_PLANES(seg1 + (size_t)sidx * SEG_U32, W)
    }

    const int row0 = rb * RB;
    #pragma unroll
    for (int r = 0; r < RB; r++) {
        *(uint32_t*)&hidden_t[(size_t)(row0 + r) * BATCH + b0 + 2 * lane] =
            pack2(accA[r].x, accA[r].y);
        *(uint32_t*)&hidden_t[(size_t)(row0 + r) * BATCH + b0 + 128 + 2 * lane] =
            pack2(accB[r].x, accB[r].y);
    }
}

// source loader for stage 2 (x_t fp32 or hidden_t bf16), pre-scaled by w
__device__ __forceinline__ float4 load_src4(const float* __restrict__ x_t,
                                            const __hip_bfloat16* __restrict__ hidden_t,
                                            int gcol, int b0, int lane, float w) {
    if (gcol < IN_DIM) {
        const float2* xp = (const float2*)&x_t[(size_t)gcol * BATCH + b0];
        float2 u0 = xp[lane], u1 = xp[64 + lane];
        return make_float4(w * u0.x, w * u0.y, w * u1.x, w * u1.y);
    } else {
        const uint16_t* hp = (const uint16_t*)&hidden_t[(size_t)(gcol - IN_DIM) * BATCH + b0];
        uint32_t q0 = *(const uint32_t*)&hp[2 * lane];
        uint32_t q1 = *(const uint32_t*)&hp[128 + 2 * lane];
        return make_float4(w * __uint_as_float(q0 << 16),
                           w * __uint_as_float(q0 & 0xFFFF0000u),
                           w * __uint_as_float(q1 << 16),
                           w * __uint_as_float(q1 & 0xFFFF0000u));
    }
}

// ---------------------------------------------------------------------------
// Stage 2: 16 waves x 8 rows = 128 rows; grid (32 tiles, 2 row groups,
// 4 chunk groups of 24). Partials [cg][r][b].
// ---------------------------------------------------------------------------
__global__ __launch_bounds__(1024, 4) void k_out(const float* __restrict__ x_t,
                                                 const __hip_bfloat16* __restrict__ hidden_t,
                                                 const float* __restrict__ wp,
                                                 const uint32_t* __restrict__ seg2,
                                                 const uint32_t* __restrict__ hdr2,
                                                 float* __restrict__ partials) {
    __shared__ uint32_t As[4 * C * 128];

    const float w  = wp[0];
    const int tile = blockIdx.x;                // 0..31
    const int rg   = blockIdx.y;                // 0..1
    const int cg   = blockIdx.z;                // 0..3
    const int lane = threadIdx.x & 63;
    const int wv   = __builtin_amdgcn_readfirstlane(threadIdx.x >> 6); // 0..15
    const int rb   = rg * 16 + wv;              // row-block 0..31
    const int b0   = tile * BT;

    float2 accA[RB], accB[RB];
    #pragma unroll
    for (int r = 0; r < RB; r++) {
        accA[r] = make_float2(0.0f, 0.0f);
        accB[r] = make_float2(0.0f, 0.0f);
    }

    float4 v[2];
    #pragma unroll
    for (int j = 0; j < 2; j++) {
        int gcol = (cg * 24) * C + wv * 2 + j;
        v[j] = load_src4(x_t, hidden_t, gcol, b0, lane, w);
    }

    #pragma unroll 1
    for (int cj = 0; cj < 24; cj++) {
        int ch = cg * 24 + cj;
        __syncthreads();
        write_acts4(As, wv * 2 + 0, lane, v[0]);
        write_acts4(As, wv * 2 + 1, lane, v[1]);
        __syncthreads();
        if (cj + 1 < 24) {
            #pragma unroll
            for (int j = 0; j < 2; j++) {
                int gcol = (ch + 1) * C + wv * 2 + j;
                v[j] = load_src4(x_t, hidden_t, gcol, b0, lane, w);
            }
        }
        int sidx = rb * S2_CH + ch;
        uint32_t W = hdr2[sidx];
        EDGE_PLANES(seg2 + (size_t)sidx * SEG_U32, W)
    }

    #pragma unroll
    for (int r = 0; r < RB; r++) {
        size_t base = ((size_t)cg * OUT_DIM + rb * RB + r) * BATCH + b0;
        *(float2*)&partials[base + 2 * lane]       = accA[r];
        *(float2*)&partials[base + 128 + 2 * lane] = accB[r];
    }
}

// ---------------------------------------------------------------------------
// k_sum: reduce 4 partial planes + transpose [r][b] -> out[b][r] (float4).
// ---------------------------------------------------------------------------
__global__ __launch_bounds__(256) void k_sum(const float* __restrict__ partials,
                                             float* __restrict__ out) {
    __shared__ float t[16][65];
    const int b0 = blockIdx.x * 64, r0 = blockIdx.y * 16;
    const int lane = threadIdx.x & 63;
    const int g4   = threadIdx.x >> 6;

    #pragma unroll
    for (int k = 0; k < 4; k++) {
        int rr = g4 * 4 + k;
        float s = 0.0f;
        #pragma unroll
        for (int cg = 0; cg < 4; cg++)
            s += partials[((size_t)cg * OUT_DIM + r0 + rr) * BATCH + b0 + lane];
        t[rr][lane] = s;
    }
    __syncthreads();
    int bb = threadIdx.x >> 2, rq = threadIdx.x & 3;
    float4 v;
    v.x = t[rq * 4 + 0][bb];
    v.y = t[rq * 4 + 1][bb];
    v.z = t[rq * 4 + 2][bb];
    v.w = t[rq * 4 + 3][bb];
    *(float4*)&out[(size_t)(b0 + bb) * OUT_DIM + r0 + rq * 4] = v;
}

// ---------------------------------------------------------------------------
extern "C" void kernel_launch(void* const* d_in, const int* in_sizes, int n_in,
                              void* d_out, int out_size, void* d_ws, size_t ws_size,
                              hipStream_t stream) {
    const float* x   = (const float*)d_in[0];
    const float* w   = (const float*)d_in[1];
    const int*   mat = (const int*)d_in[2];
    float* out = (float*)d_out;

    uint8_t* ws = (uint8_t*)d_ws;
    size_t off = 0;
    __hip_bfloat16* hidden_t = (__hip_bfloat16*)(ws + off); off += (size_t)BATCH * N_HID * 2;  // 33.6 MB
    float* x_t = (float*)(ws + off);        off += (size_t)IN_DIM * BATCH * 4;                 // 33.6 MB
    uint32_t* seg1 = (uint32_t*)(ws + off); off += (size_t)NSEG1 * SEG_U32 * 4;                //  4.19 MB
    uint32_t* seg2 = (uint32_t*)(ws + off); off += (size_t)NSEG2 * SEG_U32 * 4;                //  1.57 MB
    uint32_t* hdr1 = (uint32_t*)(ws + off); off += (size_t)NSEG1 * 4;
    uint32_t* hdr2 = (uint32_t*)(ws + off); off += (size_t)NSEG2 * 4;
    float* partials = (float*)(ws + off);   off += (size_t)4 * OUT_DIM * BATCH * 4;            // 33.6 MB
    (void)ws_size; (void)in_sizes; (void)n_in; (void)out_size;

    // v4 format is fully mask-gated: no memset needed (pad bytes never read)
    {
        int nseg = NSEG1 + NSEG2;                   // 11264 waves
        k_prep<<<(nseg + 3) / 4, 256, 0, stream>>>(mat, seg1, seg2, hdr1, hdr2);
    }
    {
        dim3 g(BATCH / 64, IN_DIM / 64);            // 128 x 16
        k_xt<<<g, 256, 0, stream>>>(x, x_t);
    }
    {
        dim3 g(BATCH / BT, N_HID / (16 * RB));      // 32 x 16 = 512 blocks
        k_hid<<<g, 1024, 0, stream>>>(x_t, w, seg1, hdr1, hidden_t);
    }
    {
        dim3 g(BATCH / BT, 2, 4);                   // 32 x 2 x 4 = 256 blocks
        k_out<<<g, 1024, 0, stream>>>(x_t, hidden_t, w, seg2, hdr2, partials);
    }
    {
        dim3 g(BATCH / 64, OUT_DIM / 16);           // 2048 blocks
        k_sum<<<g, 256, 0, stream>>>(partials, out);
    }
}

// Round 2
// 397.646 us; speedup vs baseline: 1.1266x; 1.1266x over previous
//
#include <hip/hip_runtime.h>
#include <hip/hip_bf16.h>
#include <stdint.h>

// Problem constants
#define BATCH   8192
#define IN_DIM  1024
#define N_HID   2048
#define OUT_DIM 256
#define SRC_DIM 3072

// Tiling
#define C     32                   // source columns per chunk
#define RB    16                   // rows per row-block (= rows per wave)
#define BT    256                  // batch per block (4/lane: 2l,2l+1,128+2l,128+2l+1)
#define S1_CH (IN_DIM / C)         // 32
#define S1_RB (N_HID / RB)         // 128
#define S2_CH (SRC_DIM / C)        // 96
#define S2_RB (OUT_DIM / RB)       // 16
#define NSEG1 (S1_RB * S1_CH)      // 4096
#define NSEG2 (S2_RB * S2_CH)      // 1536
#define ZSLOT 128                  // A-tile zero page (pad byte 0x80)
#define SEG_U32 128                // segment stride (512 B)

// Segment format v3 (PROVEN branchless schedule, 205us k_hid at BT=128):
//   u32[0..7]   plane-0: row r -> u16 at byte 2r (2 slot bytes, pad 0x80)
//   7 overflow planes p=1..7 at u32 8+17(p-1):
//     [0] = 16-bit row mask (rows with n > 2+4(p-1))
//     [1+r] = 4 slot bytes for row r (pad 0x80)
//   hdr: W = total planes, wave-uniform.
// R1 LESSON (v4 fully-gated format, 249us): per-slot branch gating costs
// ~70 VALU/slot (exec-mask + broken DS batching) vs ~19 here. Plane-0 MUST
// stay unconditional; pads hit the zero page. The win that survives:
// ds_read_b64 slots (BT=256) -> every DS issue/addr/extract serves 2x batches.

// A-tile: slot s (0..127) occupies 512 B; lane l ds_read_b64 at s*512 + 8l =
// bf16 pairs for batches (2l,2l+1) and (128+2l,128+2l+1). +zero page = 64.5 KB.

// ---------------------------------------------------------------------------
__global__ void k_prep(const int* __restrict__ mat,
                       uint32_t* __restrict__ seg1, uint32_t* __restrict__ seg2,
                       uint32_t* __restrict__ hdr1, uint32_t* __restrict__ hdr2) {
    int wid  = (blockIdx.x * blockDim.x + threadIdx.x) >> 6;
    int lane = threadIdx.x & 63;
    if (wid >= NSEG1 + NSEG2) return;

    int row0, col0;
    uint32_t *seg, *hdr;
    if (wid < NSEG1) {
        int rb = wid / S1_CH, ch = wid % S1_CH;
        row0 = rb * RB;          col0 = ch * C;
        seg = seg1 + (size_t)wid * SEG_U32;  hdr = hdr1 + wid;
    } else {
        int s  = wid - NSEG1;
        int rb = s / S2_CH, ch = s % S2_CH;
        row0 = N_HID + rb * RB;  col0 = ch * C;
        seg = seg2 + (size_t)s * SEG_U32;    hdr = hdr2 + s;
    }

    int n = 0;
    if (lane < RB) {
        const int* mrow = mat + (size_t)(row0 + lane) * SRC_DIM + col0;
        uint8_t* sb = (uint8_t*)seg;
        for (int c = 0; c < C; c++) {
            int code = mrow[c];
            if (code != 0) {
                uint8_t slot = (uint8_t)((code - 1) * C + c);
                if (n < 2) {
                    sb[2 * lane + n] = slot;               // plane-0 u16
                } else {
                    int j = n - 2;
                    sb[(size_t)(8 + 17 * (j >> 2) + 1 + lane) * 4 + (j & 3)] = slot;
                }
                n++;
            }
        }
    }
    int m = n;
    #pragma unroll
    for (int d = 1; d < 64; d <<= 1) m = max(m, __shfl_xor(m, d));
    uint32_t Wv = (m <= 2) ? 1u : 1u + (uint32_t)((m - 2 + 3) >> 2);

    for (uint32_t p = 1; p < Wv; p++) {
        unsigned long long b = __ballot(n > 2 + 4 * (int)(p - 1));
        if (lane == 0) seg[8 + 17 * (p - 1)] = (uint32_t)(b & 0xFFFFu);
    }
    if (lane == 0) *hdr = Wv;
}

// ---------------------------------------------------------------------------
// k_xt: transpose x[8192][1024] -> x_t[1024][8192] (fp32), 64x64 LDS tiles.
// ---------------------------------------------------------------------------
__global__ __launch_bounds__(256) void k_xt(const float* __restrict__ x,
                                            float* __restrict__ x_t) {
    __shared__ float t[64][65];
    const int b0 = blockIdx.x * 64, c0 = blockIdx.y * 64;
    {
        int r  = threadIdx.x >> 4;
        int cq = (threadIdx.x & 15) * 4;
        #pragma unroll
        for (int k = 0; k < 4; k++) {
            int rr = r + 16 * k;
            float4 v = *(const float4*)&x[(size_t)(b0 + rr) * IN_DIM + c0 + cq];
            t[rr][cq + 0] = v.x; t[rr][cq + 1] = v.y;
            t[rr][cq + 2] = v.z; t[rr][cq + 3] = v.w;
        }
    }
    __syncthreads();
    {
        int bq  = (threadIdx.x & 15) * 4;
        int cc0 = threadIdx.x >> 4;
        #pragma unroll
        for (int k = 0; k < 4; k++) {
            int cc = cc0 + 16 * k;
            float4 v;
            v.x = t[bq + 0][cc]; v.y = t[bq + 1][cc];
            v.z = t[bq + 2][cc]; v.w = t[bq + 3][cc];
            *(float4*)&x_t[(size_t)(c0 + cc) * BATCH + b0 + bq] = v;
        }
    }
}

// pack two floats as bf16 pair: low16 = first, high16 = second
__device__ __forceinline__ uint32_t pack2(float a, float b) {
    __hip_bfloat162 h = __float22bfloat162_rn(make_float2(a, b));
    union { __hip_bfloat162 h2; uint32_t u; } u;
    u.h2 = h;
    return u.u;
}

// write 4 activation slots for column c, 4 batches per lane (v pre-scaled by w)
__device__ __forceinline__ void write_acts4(uint32_t* As, int c, int lane, float4 v) {
    *(uint2*)&As[(size_t)(0 * C + c) * 128 + 2 * lane] =
        make_uint2(pack2(v.x, v.y), pack2(v.z, v.w));
    *(uint2*)&As[(size_t)(1 * C + c) * 128 + 2 * lane] =
        make_uint2(pack2(fmaxf(v.x, 0.0f), fmaxf(v.y, 0.0f)),
                   pack2(fmaxf(v.z, 0.0f), fmaxf(v.w, 0.0f)));
    float tx = 1.0f - 2.0f / (__expf(2.0f * v.x) + 1.0f);
    float ty = 1.0f - 2.0f / (__expf(2.0f * v.y) + 1.0f);
    float tz = 1.0f - 2.0f / (__expf(2.0f * v.z) + 1.0f);
    float tw = 1.0f - 2.0f / (__expf(2.0f * v.w) + 1.0f);
    *(uint2*)&As[(size_t)(2 * C + c) * 128 + 2 * lane] =
        make_uint2(pack2(tx, ty), pack2(tz, tw));
    float sx = 1.0f / (1.0f + __expf(-v.x));
    float sy = 1.0f / (1.0f + __expf(-v.y));
    float sz = 1.0f / (1.0f + __expf(-v.z));
    float sw = 1.0f / (1.0f + __expf(-v.w));
    *(uint2*)&As[(size_t)(3 * C + c) * 128 + 2 * lane] =
        make_uint2(pack2(sx, sy), pack2(sz, sw));
}

// one slot: ds_read_b64 -> 2 bf16-pairs -> 4 packed adds (4 batches/lane)
#define SLOT_ACC(R, S)                                                         \
    {                                                                          \
        uint2 q_ = *(const uint2*)&As[(size_t)(S) * 128 + 2 * lane];           \
        accA[R].x += __uint_as_float(q_.x << 16);                              \
        accA[R].y += __uint_as_float(q_.x & 0xFFFF0000u);                      \
        accB[R].x += __uint_as_float(q_.y << 16);                              \
        accB[R].y += __uint_as_float(q_.y & 0xFFFF0000u);                      \
    }

#define EDGE_PLANES(SEGBASE, WVAL)                                             \
    {                                                                          \
        const uint32_t* sp_ = (SEGBASE);                                       \
        _Pragma("unroll")                                                      \
        for (int i = 0; i < 8; i++) {                                          \
            uint32_t g = sp_[i];                                               \
            SLOT_ACC(2 * i,     g & 255u)                                      \
            SLOT_ACC(2 * i,     (g >> 8) & 255u)                               \
            SLOT_ACC(2 * i + 1, (g >> 16) & 255u)                              \
            SLOT_ACC(2 * i + 1, g >> 24)                                       \
        }                                                                      \
        for (uint32_t p = 1; p < (WVAL); p++) {                                \
            const uint32_t* pp_ = sp_ + 8 + 17 * (p - 1);                      \
            uint32_t mask = pp_[0];                                            \
            _Pragma("unroll")                                                  \
            for (int r = 0; r < RB; r++) {                                     \
                if (mask & (1u << r)) {                                        \
                    uint32_t g = pp_[1 + r];                                   \
                    SLOT_ACC(r, g & 255u)                                      \
                    SLOT_ACC(r, (g >> 8) & 255u)                               \
                    SLOT_ACC(r, (g >> 16) & 255u)                              \
                    SLOT_ACC(r, g >> 24)                                       \
                }                                                              \
            }                                                                  \
        }                                                                      \
    }

// ---------------------------------------------------------------------------
// Stage 1: 1024 thr = 16 waves x 16 rows = 256 rows; 256 batches per block.
// Grid (32 tiles, 8 row splits) = 256 blocks = 1/CU. LDS 64.5 KB.
// ---------------------------------------------------------------------------
__global__ __launch_bounds__(1024, 4) void k_hid(const float* __restrict__ x_t,
                                                 const float* __restrict__ wp,
                                                 const uint32_t* __restrict__ seg1,
                                                 const uint32_t* __restrict__ hdr1,
                                                 __hip_bfloat16* __restrict__ hidden_t) {
    __shared__ uint32_t As[(4 * C + 1) * 128];  // 64.5 KB

    const float w  = wp[0];
    const int tile = blockIdx.x;                // 0..31
    const int lane = threadIdx.x & 63;
    const int wv   = __builtin_amdgcn_readfirstlane(threadIdx.x >> 6); // 0..15
    const int rb   = blockIdx.y * 16 + wv;      // row-block 0..127
    const int b0   = tile * BT;

    if (threadIdx.x < 128) As[ZSLOT * 128 + threadIdx.x] = 0u;

    float2 accA[RB], accB[RB];
    #pragma unroll
    for (int r = 0; r < RB; r++) {
        accA[r] = make_float2(0.0f, 0.0f);
        accB[r] = make_float2(0.0f, 0.0f);
    }

    // prefetch chunk 0: each wave owns 2 columns, 4 batches/lane
    float4 v[2];
    #pragma unroll
    for (int j = 0; j < 2; j++) {
        int gcol = wv * 2 + j;
        const float2* xp = (const float2*)&x_t[(size_t)gcol * BATCH + b0];
        float2 u0 = xp[lane], u1 = xp[64 + lane];
        v[j] = make_float4(w * u0.x, w * u0.y, w * u1.x, w * u1.y);
    }

    #pragma unroll 1
    for (int ch = 0; ch < S1_CH; ch++) {
        __syncthreads();                        // edge-phase(ch-1) done
        write_acts4(As, wv * 2 + 0, lane, v[0]);
        write_acts4(As, wv * 2 + 1, lane, v[1]);
        __syncthreads();                        // acts visible
        if (ch + 1 < S1_CH) {                   // prefetch next chunk
            #pragma unroll
            for (int j = 0; j < 2; j++) {
                int gcol = (ch + 1) * C + wv * 2 + j;
                const float2* xp = (const float2*)&x_t[(size_t)gcol * BATCH + b0];
                float2 u0 = xp[lane], u1 = xp[64 + lane];
                v[j] = make_float4(w * u0.x, w * u0.y, w * u1.x, w * u1.y);
            }
        }
        int sidx = rb * S1_CH + ch;
        uint32_t W = hdr1[sidx];
        EDGE_PLANES(seg1 + (size_t)sidx * SEG_U32, W)
    }

    const int row0 = rb * RB;
    #pragma unroll
    for (int r = 0; r < RB; r++) {
        *(uint32_t*)&hidden_t[(size_t)(row0 + r) * BATCH + b0 + 2 * lane] =
            pack2(accA[r].x, accA[r].y);
        *(uint32_t*)&hidden_t[(size_t)(row0 + r) * BATCH + b0 + 128 + 2 * lane] =
            pack2(accB[r].x, accB[r].y);
    }
}

// source loader for stage 2 (x_t fp32 or hidden_t bf16), pre-scaled by w
__device__ __forceinline__ float4 load_src4(const float* __restrict__ x_t,
                                            const __hip_bfloat16* __restrict__ hidden_t,
                                            int gcol, int b0, int lane, float w) {
    if (gcol < IN_DIM) {
        const float2* xp = (const float2*)&x_t[(size_t)gcol * BATCH + b0];
        float2 u0 = xp[lane], u1 = xp[64 + lane];
        return make_float4(w * u0.x, w * u0.y, w * u1.x, w * u1.y);
    } else {
        const uint16_t* hp = (const uint16_t*)&hidden_t[(size_t)(gcol - IN_DIM) * BATCH + b0];
        uint32_t q0 = *(const uint32_t*)&hp[2 * lane];
        uint32_t q1 = *(const uint32_t*)&hp[128 + 2 * lane];
        return make_float4(w * __uint_as_float(q0 << 16),
                           w * __uint_as_float(q0 & 0xFFFF0000u),
                           w * __uint_as_float(q1 << 16),
                           w * __uint_as_float(q1 & 0xFFFF0000u));
    }
}

// ---------------------------------------------------------------------------
// Stage 2: 16 waves x 16 rows = ALL 256 out rows; 256 batches per block.
// Grid (32 tiles, 8 chunk groups of 12) = 256 blocks. Partials [cg][r][b].
// ---------------------------------------------------------------------------
__global__ __launch_bounds__(1024, 4) void k_out(const float* __restrict__ x_t,
                                                 const __hip_bfloat16* __restrict__ hidden_t,
                                                 const float* __restrict__ wp,
                                                 const uint32_t* __restrict__ seg2,
                                                 const uint32_t* __restrict__ hdr2,
                                                 float* __restrict__ partials) {
    __shared__ uint32_t As[(4 * C + 1) * 128];

    const float w  = wp[0];
    const int tile = blockIdx.x;                // 0..31
    const int cg   = blockIdx.y;                // 0..7
    const int lane = threadIdx.x & 63;
    const int wv   = __builtin_amdgcn_readfirstlane(threadIdx.x >> 6); // 0..15
    const int b0   = tile * BT;

    if (threadIdx.x < 128) As[ZSLOT * 128 + threadIdx.x] = 0u;

    float2 accA[RB], accB[RB];
    #pragma unroll
    for (int r = 0; r < RB; r++) {
        accA[r] = make_float2(0.0f, 0.0f);
        accB[r] = make_float2(0.0f, 0.0f);
    }

    float4 v[2];
    #pragma unroll
    for (int j = 0; j < 2; j++) {
        int gcol = (cg * 12) * C + wv * 2 + j;
        v[j] = load_src4(x_t, hidden_t, gcol, b0, lane, w);
    }

    #pragma unroll 1
    for (int cj = 0; cj < 12; cj++) {
        int ch = cg * 12 + cj;
        __syncthreads();
        write_acts4(As, wv * 2 + 0, lane, v[0]);
        write_acts4(As, wv * 2 + 1, lane, v[1]);
        __syncthreads();
        if (cj + 1 < 12) {
            #pragma unroll
            for (int j = 0; j < 2; j++) {
                int gcol = (ch + 1) * C + wv * 2 + j;
                v[j] = load_src4(x_t, hidden_t, gcol, b0, lane, w);
            }
        }
        int sidx = wv * S2_CH + ch;              // wv = row-block 0..15
        uint32_t W = hdr2[sidx];
        EDGE_PLANES(seg2 + (size_t)sidx * SEG_U32, W)
    }

    #pragma unroll
    for (int r = 0; r < RB; r++) {
        size_t base = ((size_t)cg * OUT_DIM + wv * RB + r) * BATCH + b0;
        *(float2*)&partials[base + 2 * lane]       = accA[r];
        *(float2*)&partials[base + 128 + 2 * lane] = accB[r];
    }
}

// ---------------------------------------------------------------------------
// k_sum: reduce 8 partial planes + transpose [r][b] -> out[b][r] (float4).
// ---------------------------------------------------------------------------
__global__ __launch_bounds__(256) void k_sum(const float* __restrict__ partials,
                                             float* __restrict__ out) {
    __shared__ float t[16][65];
    const int b0 = blockIdx.x * 64, r0 = blockIdx.y * 16;
    const int lane = threadIdx.x & 63;
    const int g4   = threadIdx.x >> 6;

    #pragma unroll
    for (int k = 0; k < 4; k++) {
        int rr = g4 * 4 + k;
        float s = 0.0f;
        #pragma unroll
        for (int cg = 0; cg < 8; cg++)
            s += partials[((size_t)cg * OUT_DIM + r0 + rr) * BATCH + b0 + lane];
        t[rr][lane] = s;
    }
    __syncthreads();
    int bb = threadIdx.x >> 2, rq = threadIdx.x & 3;
    float4 v;
    v.x = t[rq * 4 + 0][bb];
    v.y = t[rq * 4 + 1][bb];
    v.z = t[rq * 4 + 2][bb];
    v.w = t[rq * 4 + 3][bb];
    *(float4*)&out[(size_t)(b0 + bb) * OUT_DIM + r0 + rq * 4] = v;
}

// ---------------------------------------------------------------------------
extern "C" void kernel_launch(void* const* d_in, const int* in_sizes, int n_in,
                              void* d_out, int out_size, void* d_ws, size_t ws_size,
                              hipStream_t stream) {
    const float* x   = (const float*)d_in[0];
    const float* w   = (const float*)d_in[1];
    const int*   mat = (const int*)d_in[2];
    float* out = (float*)d_out;

    uint8_t* ws = (uint8_t*)d_ws;
    size_t off = 0;
    __hip_bfloat16* hidden_t = (__hip_bfloat16*)(ws + off); off += (size_t)BATCH * N_HID * 2;  // 33.6 MB
    float* x_t = (float*)(ws + off);        off += (size_t)IN_DIM * BATCH * 4;                 // 33.6 MB
    uint32_t* seg1 = (uint32_t*)(ws + off); off += (size_t)NSEG1 * SEG_U32 * 4;                //  2.10 MB
    uint32_t* seg2 = (uint32_t*)(ws + off); off += (size_t)NSEG2 * SEG_U32 * 4;                //  0.79 MB
    uint32_t* hdr1 = (uint32_t*)(ws + off); off += (size_t)NSEG1 * 4;
    uint32_t* hdr2 = (uint32_t*)(ws + off); off += (size_t)NSEG2 * 4;
    float* partials = (float*)(ws + off);   off += (size_t)8 * OUT_DIM * BATCH * 4;            // 67.1 MB
    (void)ws_size; (void)in_sizes; (void)n_in; (void)out_size;

    hipMemsetAsync(seg1, 0x80, (size_t)(NSEG1 + NSEG2) * SEG_U32 * 4, stream);

    {
        int nseg = NSEG1 + NSEG2;                   // 5632 waves
        k_prep<<<(nseg + 3) / 4, 256, 0, stream>>>(mat, seg1, seg2, hdr1, hdr2);
    }
    {
        dim3 g(BATCH / 64, IN_DIM / 64);            // 128 x 16
        k_xt<<<g, 256, 0, stream>>>(x, x_t);
    }
    {
        dim3 g(BATCH / BT, 8);                      // 32 x 8 = 256 blocks
        k_hid<<<g, 1024, 0, stream>>>(x_t, w, seg1, hdr1, hidden_t);
    }
    {
        dim3 g(BATCH / BT, 8);                      // 32 x 8 = 256 blocks
        k_out<<<g, 1024, 0, stream>>>(x_t, hidden_t, w, seg2, hdr2, partials);
    }
    {
        dim3 g(BATCH / 64, OUT_DIM / 16);           // 2048 blocks
        k_sum<<<g, 256, 0, stream>>>(partials, out);
    }
}

// Round 3
// 336.413 us; speedup vs baseline: 1.3316x; 1.1820x over previous
//
#include <hip/hip_runtime.h>
#include <hip/hip_bf16.h>
#include <stdint.h>

// Problem constants
#define BATCH   8192
#define IN_DIM  1024
#define N_HID   2048
#define OUT_DIM 256
#define SRC_DIM 3072

// Tiling
#define C     32                   // source columns per chunk
#define RB    16                   // rows per row-block (= rows per wave)
#define BT    256                  // batch per block (4/lane: 2l,2l+1,128+2l,128+2l+1)
#define S1_CH (IN_DIM / C)         // 32
#define S1_RB (N_HID / RB)         // 128
#define S2_CH (SRC_DIM / C)        // 96
#define S2_RB (OUT_DIM / RB)       // 16
#define NSEG1 (S1_RB * S1_CH)      // 4096
#define NSEG2 (S2_RB * S2_CH)      // 1536
#define ZSLOT 128                  // A-tile zero page (pad byte 0x80)
#define SEG_U32 128                // segment stride (512 B)
#define ABUF_U32 ((4 * C + 1) * 128)  // 16512 u32 = 64.5 KB per A-tile buffer

// Segment format v3 (PROVEN branchless schedule):
//   u32[0..7]   plane-0: row r -> u16 at byte 2r (2 slot bytes, pad 0x80)
//   7 overflow planes p=1..7 at u32 8+17(p-1):
//     [0] = 16-bit row mask (rows with n > 2+4(p-1))
//     [1+r] = 4 slot bytes for row r (pad 0x80)
// R1 LESSON: per-slot branch gating costs ~70 VALU/slot; plane-0 stays
// unconditional, pads hit the zero page.
// R2 LESSON: BT=256 halved per-element VALU but grid fell to 1 block/CU;
// the 2 barriers/chunk exposed ~60us of inter-wave skew previously hidden
// by cross-block overlap. Fix: DOUBLE-BUFFERED A-tile (129 KB LDS), one
// barrier/chunk, acts(ch+1) writes overlap edge(ch) reads.

// ---------------------------------------------------------------------------
__global__ void k_prep(const int* __restrict__ mat,
                       uint32_t* __restrict__ seg1, uint32_t* __restrict__ seg2,
                       uint32_t* __restrict__ hdr1, uint32_t* __restrict__ hdr2) {
    int wid  = (blockIdx.x * blockDim.x + threadIdx.x) >> 6;
    int lane = threadIdx.x & 63;
    if (wid >= NSEG1 + NSEG2) return;

    int row0, col0;
    uint32_t *seg, *hdr;
    if (wid < NSEG1) {
        int rb = wid / S1_CH, ch = wid % S1_CH;
        row0 = rb * RB;          col0 = ch * C;
        seg = seg1 + (size_t)wid * SEG_U32;  hdr = hdr1 + wid;
    } else {
        int s  = wid - NSEG1;
        int rb = s / S2_CH, ch = s % S2_CH;
        row0 = N_HID + rb * RB;  col0 = ch * C;
        seg = seg2 + (size_t)s * SEG_U32;    hdr = hdr2 + s;
    }

    int n = 0;
    if (lane < RB) {
        const int* mrow = mat + (size_t)(row0 + lane) * SRC_DIM + col0;
        uint8_t* sb = (uint8_t*)seg;
        for (int c = 0; c < C; c++) {
            int code = mrow[c];
            if (code != 0) {
                uint8_t slot = (uint8_t)((code - 1) * C + c);
                if (n < 2) {
                    sb[2 * lane + n] = slot;               // plane-0 u16
                } else {
                    int j = n - 2;
                    sb[(size_t)(8 + 17 * (j >> 2) + 1 + lane) * 4 + (j & 3)] = slot;
                }
                n++;
            }
        }
    }
    int m = n;
    #pragma unroll
    for (int d = 1; d < 64; d <<= 1) m = max(m, __shfl_xor(m, d));
    uint32_t Wv = (m <= 2) ? 1u : 1u + (uint32_t)((m - 2 + 3) >> 2);

    for (uint32_t p = 1; p < Wv; p++) {
        unsigned long long b = __ballot(n > 2 + 4 * (int)(p - 1));
        if (lane == 0) seg[8 + 17 * (p - 1)] = (uint32_t)(b & 0xFFFFu);
    }
    if (lane == 0) *hdr = Wv;
}

// ---------------------------------------------------------------------------
// k_xt: transpose x[8192][1024] -> x_t[1024][8192] (fp32), 64x64 LDS tiles.
// ---------------------------------------------------------------------------
__global__ __launch_bounds__(256) void k_xt(const float* __restrict__ x,
                                            float* __restrict__ x_t) {
    __shared__ float t[64][65];
    const int b0 = blockIdx.x * 64, c0 = blockIdx.y * 64;
    {
        int r  = threadIdx.x >> 4;
        int cq = (threadIdx.x & 15) * 4;
        #pragma unroll
        for (int k = 0; k < 4; k++) {
            int rr = r + 16 * k;
            float4 v = *(const float4*)&x[(size_t)(b0 + rr) * IN_DIM + c0 + cq];
            t[rr][cq + 0] = v.x; t[rr][cq + 1] = v.y;
            t[rr][cq + 2] = v.z; t[rr][cq + 3] = v.w;
        }
    }
    __syncthreads();
    {
        int bq  = (threadIdx.x & 15) * 4;
        int cc0 = threadIdx.x >> 4;
        #pragma unroll
        for (int k = 0; k < 4; k++) {
            int cc = cc0 + 16 * k;
            float4 v;
            v.x = t[bq + 0][cc]; v.y = t[bq + 1][cc];
            v.z = t[bq + 2][cc]; v.w = t[bq + 3][cc];
            *(float4*)&x_t[(size_t)(c0 + cc) * BATCH + b0 + bq] = v;
        }
    }
}

// pack two floats as bf16 pair: low16 = first, high16 = second
__device__ __forceinline__ uint32_t pack2(float a, float b) {
    __hip_bfloat162 h = __float22bfloat162_rn(make_float2(a, b));
    union { __hip_bfloat162 h2; uint32_t u; } u;
    u.h2 = h;
    return u.u;
}

__device__ __forceinline__ float rcp_f(float x) { return __builtin_amdgcn_rcpf(x); }

// write 4 activation slots for column c, 4 batches per lane (v pre-scaled by w).
// Trans budget/elem: 1 v_exp + 2 v_rcp (no precise-divide sequences).
// sigmoid = rcp(1+E), tanh = 2*rcp(1+E^2)-1  with E = exp(-v)  (robust at inf).
__device__ __forceinline__ void write_acts4(uint32_t* As, int c, int lane, float4 v) {
    *(uint2*)&As[(size_t)(0 * C + c) * 128 + 2 * lane] =
        make_uint2(pack2(v.x, v.y), pack2(v.z, v.w));
    *(uint2*)&As[(size_t)(1 * C + c) * 128 + 2 * lane] =
        make_uint2(pack2(fmaxf(v.x, 0.0f), fmaxf(v.y, 0.0f)),
                   pack2(fmaxf(v.z, 0.0f), fmaxf(v.w, 0.0f)));
    float ex = __expf(-v.x), ey = __expf(-v.y);
    float ez = __expf(-v.z), ew = __expf(-v.w);
    float tx = fmaf(2.0f, rcp_f(fmaf(ex, ex, 1.0f)), -1.0f);
    float ty = fmaf(2.0f, rcp_f(fmaf(ey, ey, 1.0f)), -1.0f);
    float tz = fmaf(2.0f, rcp_f(fmaf(ez, ez, 1.0f)), -1.0f);
    float tw = fmaf(2.0f, rcp_f(fmaf(ew, ew, 1.0f)), -1.0f);
    *(uint2*)&As[(size_t)(2 * C + c) * 128 + 2 * lane] =
        make_uint2(pack2(tx, ty), pack2(tz, tw));
    float sx = rcp_f(1.0f + ex), sy = rcp_f(1.0f + ey);
    float sz = rcp_f(1.0f + ez), sw = rcp_f(1.0f + ew);
    *(uint2*)&As[(size_t)(3 * C + c) * 128 + 2 * lane] =
        make_uint2(pack2(sx, sy), pack2(sz, sw));
}

// one slot: ds_read_b64 -> 2 bf16-pairs -> 4 packed adds (4 batches/lane)
#define SLOT_ACC(AB, R, S)                                                     \
    {                                                                          \
        uint2 q_ = *(const uint2*)&(AB)[(size_t)(S) * 128 + 2 * lane];         \
        accA[R].x += __uint_as_float(q_.x << 16);                              \
        accA[R].y += __uint_as_float(q_.x & 0xFFFF0000u);                      \
        accB[R].x += __uint_as_float(q_.y << 16);                              \
        accB[R].y += __uint_as_float(q_.y & 0xFFFF0000u);                      \
    }

#define EDGE_PLANES(AB, SEGBASE, WVAL)                                         \
    {                                                                          \
        const uint32_t* sp_ = (SEGBASE);                                       \
        _Pragma("unroll")                                                      \
        for (int i = 0; i < 8; i++) {                                          \
            uint32_t g = sp_[i];                                               \
            SLOT_ACC(AB, 2 * i,     g & 255u)                                  \
            SLOT_ACC(AB, 2 * i,     (g >> 8) & 255u)                           \
            SLOT_ACC(AB, 2 * i + 1, (g >> 16) & 255u)                          \
            SLOT_ACC(AB, 2 * i + 1, g >> 24)                                   \
        }                                                                      \
        for (uint32_t p = 1; p < (WVAL); p++) {                                \
            const uint32_t* pp_ = sp_ + 8 + 17 * (p - 1);                      \
            uint32_t mask = pp_[0];                                            \
            _Pragma("unroll")                                                  \
            for (int r = 0; r < RB; r++) {                                     \
                if (mask & (1u << r)) {                                        \
                    uint32_t g = pp_[1 + r];                                   \
                    SLOT_ACC(AB, r, g & 255u)                                  \
                    SLOT_ACC(AB, r, (g >> 8) & 255u)                           \
                    SLOT_ACC(AB, r, (g >> 16) & 255u)                          \
                    SLOT_ACC(AB, r, g >> 24)                                   \
                }                                                              \
            }                                                                  \
        }                                                                      \
    }

// ---------------------------------------------------------------------------
// Stage 1: 16 waves x 16 rows = 256 rows; 256 batches per block.
// Grid (32 tiles, 8 row splits) = 256 blocks. LDS 2 x 64.5 KB (dbuf),
// ONE barrier per chunk; acts(ch+1) writes overlap edge(ch) reads.
// ---------------------------------------------------------------------------
__global__ __launch_bounds__(1024, 4) void k_hid(const float* __restrict__ x_t,
                                                 const float* __restrict__ wp,
                                                 const uint32_t* __restrict__ seg1,
                                                 const uint32_t* __restrict__ hdr1,
                                                 __hip_bfloat16* __restrict__ hidden_t) {
    __shared__ uint32_t As[2 * ABUF_U32];       // 129 KB

    const float w  = wp[0];
    const int tile = blockIdx.x;                // 0..31
    const int lane = threadIdx.x & 63;
    const int wv   = __builtin_amdgcn_readfirstlane(threadIdx.x >> 6); // 0..15
    const int rb   = blockIdx.y * 16 + wv;      // row-block 0..127
    const int b0   = tile * BT;

    if (threadIdx.x < 128) {                    // both zero pages
        As[ZSLOT * 128 + threadIdx.x] = 0u;
        As[ABUF_U32 + ZSLOT * 128 + threadIdx.x] = 0u;
    }

    float2 accA[RB], accB[RB];
    #pragma unroll
    for (int r = 0; r < RB; r++) {
        accA[r] = make_float2(0.0f, 0.0f);
        accB[r] = make_float2(0.0f, 0.0f);
    }

    // prologue: acts(0) into buf0; prefetch v for chunk 1
    float4 v[2];
    #pragma unroll
    for (int j = 0; j < 2; j++) {
        int gcol = wv * 2 + j;
        const float2* xp = (const float2*)&x_t[(size_t)gcol * BATCH + b0];
        float2 u0 = xp[lane], u1 = xp[64 + lane];
        v[j] = make_float4(w * u0.x, w * u0.y, w * u1.x, w * u1.y);
    }
    write_acts4(As, wv * 2 + 0, lane, v[0]);
    write_acts4(As, wv * 2 + 1, lane, v[1]);
    #pragma unroll
    for (int j = 0; j < 2; j++) {
        int gcol = C + wv * 2 + j;
        const float2* xp = (const float2*)&x_t[(size_t)gcol * BATCH + b0];
        float2 u0 = xp[lane], u1 = xp[64 + lane];
        v[j] = make_float4(w * u0.x, w * u0.y, w * u1.x, w * u1.y);
    }
    __syncthreads();

    #pragma unroll 1
    for (int ch = 0; ch < S1_CH; ch++) {
        uint32_t* cur = As + (size_t)(ch & 1) * ABUF_U32;
        uint32_t* nxt = As + (size_t)((ch + 1) & 1) * ABUF_U32;
        if (ch + 1 < S1_CH) {
            write_acts4(nxt, wv * 2 + 0, lane, v[0]);
            write_acts4(nxt, wv * 2 + 1, lane, v[1]);
            if (ch + 2 < S1_CH) {
                #pragma unroll
                for (int j = 0; j < 2; j++) {
                    int gcol = (ch + 2) * C + wv * 2 + j;
                    const float2* xp = (const float2*)&x_t[(size_t)gcol * BATCH + b0];
                    float2 u0 = xp[lane], u1 = xp[64 + lane];
                    v[j] = make_float4(w * u0.x, w * u0.y, w * u1.x, w * u1.y);
                }
            }
        }
        int sidx = rb * S1_CH + ch;
        uint32_t W = hdr1[sidx];
        EDGE_PLANES(cur, seg1 + (size_t)sidx * SEG_U32, W)
        __syncthreads();                        // acts(ch+1) ready; edge(ch) drained
    }

    const int row0 = rb * RB;
    #pragma unroll
    for (int r = 0; r < RB; r++) {
        *(uint32_t*)&hidden_t[(size_t)(row0 + r) * BATCH + b0 + 2 * lane] =
            pack2(accA[r].x, accA[r].y);
        *(uint32_t*)&hidden_t[(size_t)(row0 + r) * BATCH + b0 + 128 + 2 * lane] =
            pack2(accB[r].x, accB[r].y);
    }
}

// source loader for stage 2 (x_t fp32 or hidden_t bf16), pre-scaled by w
__device__ __forceinline__ float4 load_src4(const float* __restrict__ x_t,
                                            const __hip_bfloat16* __restrict__ hidden_t,
                                            int gcol, int b0, int lane, float w) {
    if (gcol < IN_DIM) {
        const float2* xp = (const float2*)&x_t[(size_t)gcol * BATCH + b0];
        float2 u0 = xp[lane], u1 = xp[64 + lane];
        return make_float4(w * u0.x, w * u0.y, w * u1.x, w * u1.y);
    } else {
        const uint16_t* hp = (const uint16_t*)&hidden_t[(size_t)(gcol - IN_DIM) * BATCH + b0];
        uint32_t q0 = *(const uint32_t*)&hp[2 * lane];
        uint32_t q1 = *(const uint32_t*)&hp[128 + 2 * lane];
        return make_float4(w * __uint_as_float(q0 << 16),
                           w * __uint_as_float(q0 & 0xFFFF0000u),
                           w * __uint_as_float(q1 << 16),
                           w * __uint_as_float(q1 & 0xFFFF0000u));
    }
}

// ---------------------------------------------------------------------------
// Stage 2: 16 waves x 16 rows = ALL 256 out rows; 256 batches per block.
// Grid (32 tiles, 8 chunk groups of 12) = 256 blocks. Dbuf as in k_hid.
// ---------------------------------------------------------------------------
__global__ __launch_bounds__(1024, 4) void k_out(const float* __restrict__ x_t,
                                                 const __hip_bfloat16* __restrict__ hidden_t,
                                                 const float* __restrict__ wp,
                                                 const uint32_t* __restrict__ seg2,
                                                 const uint32_t* __restrict__ hdr2,
                                                 float* __restrict__ partials) {
    __shared__ uint32_t As[2 * ABUF_U32];

    const float w  = wp[0];
    const int tile = blockIdx.x;                // 0..31
    const int cg   = blockIdx.y;                // 0..7
    const int lane = threadIdx.x & 63;
    const int wv   = __builtin_amdgcn_readfirstlane(threadIdx.x >> 6); // 0..15
    const int b0   = tile * BT;

    if (threadIdx.x < 128) {
        As[ZSLOT * 128 + threadIdx.x] = 0u;
        As[ABUF_U32 + ZSLOT * 128 + threadIdx.x] = 0u;
    }

    float2 accA[RB], accB[RB];
    #pragma unroll
    for (int r = 0; r < RB; r++) {
        accA[r] = make_float2(0.0f, 0.0f);
        accB[r] = make_float2(0.0f, 0.0f);
    }

    float4 v[2];
    #pragma unroll
    for (int j = 0; j < 2; j++)
        v[j] = load_src4(x_t, hidden_t, (cg * 12) * C + wv * 2 + j, b0, lane, w);
    write_acts4(As, wv * 2 + 0, lane, v[0]);
    write_acts4(As, wv * 2 + 1, lane, v[1]);
    #pragma unroll
    for (int j = 0; j < 2; j++)
        v[j] = load_src4(x_t, hidden_t, (cg * 12 + 1) * C + wv * 2 + j, b0, lane, w);
    __syncthreads();

    #pragma unroll 1
    for (int cj = 0; cj < 12; cj++) {
        int ch = cg * 12 + cj;
        uint32_t* cur = As + (size_t)(cj & 1) * ABUF_U32;
        uint32_t* nxt = As + (size_t)((cj + 1) & 1) * ABUF_U32;
        if (cj + 1 < 12) {
            write_acts4(nxt, wv * 2 + 0, lane, v[0]);
            write_acts4(nxt, wv * 2 + 1, lane, v[1]);
            if (cj + 2 < 12) {
                #pragma unroll
                for (int j = 0; j < 2; j++)
                    v[j] = load_src4(x_t, hidden_t, (ch + 2) * C + wv * 2 + j, b0, lane, w);
            }
        }
        int sidx = wv * S2_CH + ch;              // wv = row-block 0..15
        uint32_t W = hdr2[sidx];
        EDGE_PLANES(cur, seg2 + (size_t)sidx * SEG_U32, W)
        __syncthreads();
    }

    #pragma unroll
    for (int r = 0; r < RB; r++) {
        size_t base = ((size_t)cg * OUT_DIM + wv * RB + r) * BATCH + b0;
        *(float2*)&partials[base + 2 * lane]       = accA[r];
        *(float2*)&partials[base + 128 + 2 * lane] = accB[r];
    }
}

// ---------------------------------------------------------------------------
// k_sum: reduce 8 partial planes + transpose [r][b] -> out[b][r] (float4).
// ---------------------------------------------------------------------------
__global__ __launch_bounds__(256) void k_sum(const float* __restrict__ partials,
                                             float* __restrict__ out) {
    __shared__ float t[16][65];
    const int b0 = blockIdx.x * 64, r0 = blockIdx.y * 16;
    const int lane = threadIdx.x & 63;
    const int g4   = threadIdx.x >> 6;

    #pragma unroll
    for (int k = 0; k < 4; k++) {
        int rr = g4 * 4 + k;
        float s = 0.0f;
        #pragma unroll
        for (int cg = 0; cg < 8; cg++)
            s += partials[((size_t)cg * OUT_DIM + r0 + rr) * BATCH + b0 + lane];
        t[rr][lane] = s;
    }
    __syncthreads();
    int bb = threadIdx.x >> 2, rq = threadIdx.x & 3;
    float4 v;
    v.x = t[rq * 4 + 0][bb];
    v.y = t[rq * 4 + 1][bb];
    v.z = t[rq * 4 + 2][bb];
    v.w = t[rq * 4 + 3][bb];
    *(float4*)&out[(size_t)(b0 + bb) * OUT_DIM + r0 + rq * 4] = v;
}

// ---------------------------------------------------------------------------
extern "C" void kernel_launch(void* const* d_in, const int* in_sizes, int n_in,
                              void* d_out, int out_size, void* d_ws, size_t ws_size,
                              hipStream_t stream) {
    const float* x   = (const float*)d_in[0];
    const float* w   = (const float*)d_in[1];
    const int*   mat = (const int*)d_in[2];
    float* out = (float*)d_out;

    uint8_t* ws = (uint8_t*)d_ws;
    size_t off = 0;
    __hip_bfloat16* hidden_t = (__hip_bfloat16*)(ws + off); off += (size_t)BATCH * N_HID * 2;  // 33.6 MB
    float* x_t = (float*)(ws + off);        off += (size_t)IN_DIM * BATCH * 4;                 // 33.6 MB
    uint32_t* seg1 = (uint32_t*)(ws + off); off += (size_t)NSEG1 * SEG_U32 * 4;                //  2.10 MB
    uint32_t* seg2 = (uint32_t*)(ws + off); off += (size_t)NSEG2 * SEG_U32 * 4;                //  0.79 MB
    uint32_t* hdr1 = (uint32_t*)(ws + off); off += (size_t)NSEG1 * 4;
    uint32_t* hdr2 = (uint32_t*)(ws + off); off += (size_t)NSEG2 * 4;
    float* partials = (float*)(ws + off);   off += (size_t)8 * OUT_DIM * BATCH * 4;            // 67.1 MB
    (void)ws_size; (void)in_sizes; (void)n_in; (void)out_size;

    hipMemsetAsync(seg1, 0x80, (size_t)(NSEG1 + NSEG2) * SEG_U32 * 4, stream);

    {
        int nseg = NSEG1 + NSEG2;                   // 5632 waves
        k_prep<<<(nseg + 3) / 4, 256, 0, stream>>>(mat, seg1, seg2, hdr1, hdr2);
    }
    {
        dim3 g(BATCH / 64, IN_DIM / 64);            // 128 x 16
        k_xt<<<g, 256, 0, stream>>>(x, x_t);
    }
    {
        dim3 g(BATCH / BT, 8);                      // 32 x 8 = 256 blocks
        k_hid<<<g, 1024, 0, stream>>>(x_t, w, seg1, hdr1, hidden_t);
    }
    {
        dim3 g(BATCH / BT, 8);                      // 32 x 8 = 256 blocks
        k_out<<<g, 1024, 0, stream>>>(x_t, hidden_t, w, seg2, hdr2, partials);
    }
    {
        dim3 g(BATCH / 64, OUT_DIM / 16);           // 2048 blocks
        k_sum<<<g, 256, 0, stream>>>(partials, out);
    }
}